// Round 14
// baseline (74.649 us; speedup 1.0000x reference)
//
#include <hip/hip_runtime.h>

#define NN      4096   // total nodes
#define BG      64     // graphs
#define NPG_    64     // nodes per graph
#define LT_     128
#define LL_     32
#define D_      256
#define OUT_    1024
#define VOCAB_  50000

typedef __attribute__((ext_vector_type(8))) short bf16x8;   // 8 bf16 = 4 VGPR
typedef __attribute__((ext_vector_type(4))) float f32x4;

__device__ __forceinline__ unsigned short f2bf_rne(float f) {
    union { float f; unsigned u; } a; a.f = f;
    const unsigned r = a.u + 0x7FFFu + ((a.u >> 16) & 1u);
    return (unsigned short)(r >> 16);
}
__device__ __forceinline__ float bf2f(unsigned short h) {
    union { unsigned u; float f; } a; a.u = ((unsigned)h) << 16;
    return a.f;
}
// split f32 into bf16 hi + lo; v ~= hi + lo, err <= 2^-18 |v| (W pack only)
__device__ __forceinline__ void split_bf16(float v, unsigned short& hi, unsigned short& lo) {
    union { float f; unsigned u; } a; a.f = v;
    const unsigned hu = (a.u + 0x8000u) & 0xFFFF0000u;
    union { unsigned u; float f; } h; h.u = hu;
    const float r = v - h.f;                  // exact
    union { float f; unsigned u; } b; b.f = r;
    hi = (unsigned short)(hu >> 16);
    lo = (unsigned short)(((b.u + 0x8000u) & 0xFFFF0000u) >> 16);
}

// ---------------- K1: LABEL gather (first) + word_emb->bf16 conv + W pack ----------------
// Blocks [0, NN): per-node label gather (f32 table) -> xb_l bf16  [longest-latency first]
// Blocks [NN, NN+convBlocks): grid-stride RNE conversion of word_emb -> wtab
// Blocks [NN+convBlocks, +256): pack W into Wpk[nt][ks][plane(4)][lane][e]
__global__ __launch_bounds__(256) void prep_label_kernel(
    const float* __restrict__ word_emb,
    const float* __restrict__ Wg_text,
    const float* __restrict__ Wg_label,
    const int convBlocks,
    const int*   __restrict__ label_ids,
    const int*   __restrict__ label_len,
    const float* __restrict__ label_emb,
    unsigned short* __restrict__ wtab,
    unsigned short* __restrict__ Wpk,
    unsigned short* __restrict__ xb_l)   // [NN, D] bf16
{
    const int tid = threadIdx.x;

    if (blockIdx.x < NN) {
        // ---- label gather role (proven 4-way wave-split f32 path) ----
        __shared__ int   sIds[LL_];
        __shared__ float red[4][D_];

        const int n    = blockIdx.x;
        const int wave = tid >> 6;
        const int lane = tid & 63;

        if (tid < LL_) sIds[tid] = label_ids[(size_t)n * LL_ + tid];
        const int ll = label_len[n];
        __syncthreads();

        float4 aL = make_float4(0.f, 0.f, 0.f, 0.f);
        {
            const float* __restrict__ bp = label_emb + (size_t)lane * 4;
            #pragma unroll 8
            for (int l = wave; l < ll; l += 4) {
                const float4 v = *reinterpret_cast<const float4*>(bp + (size_t)sIds[l] * D_);
                aL.x += v.x; aL.y += v.y; aL.z += v.z; aL.w += v.w;
            }
        }
        *reinterpret_cast<float4*>(&red[wave][lane * 4]) = aL;
        __syncthreads();
        const float lv = (red[0][tid] + red[1][tid]) + (red[2][tid] + red[3][tid]);
        xb_l[(size_t)n * D_ + tid] = f2bf_rne(lv);
        return;
    }

    if (blockIdx.x < NN + convBlocks) {
        const int cb = blockIdx.x - NN;
        const int total4 = VOCAB_ * D_ / 4;
        const int stride = convBlocks * 256;
        for (int i = cb * 256 + tid; i < total4; i += stride) {
            const float4 v = *reinterpret_cast<const float4*>(word_emb + (size_t)i * 4);
            ushort4 o;
            o.x = f2bf_rne(v.x); o.y = f2bf_rne(v.y);
            o.z = f2bf_rne(v.z); o.w = f2bf_rne(v.w);
            *reinterpret_cast<ushort4*>(wtab + (size_t)i * 4) = o;
        }
        return;
    }

    // ---- W pack role ----
    const int b   = blockIdx.x - NN - convBlocks;   // mat(2) x nt(16) x ks(8)
    const int mat = b >> 7;
    const int nt  = (b >> 3) & 15;
    const int ks  = b & 7;
    const float* __restrict__ W = mat ? Wg_label : Wg_text;
    #pragma unroll
    for (int r = 0; r < 2; ++r) {
        const int idx = tid + 256 * r;     // 0..511 = 32 k x 16 cols
        const int kl  = idx >> 4;
        const int c16 = idx & 15;
        const int k   = ks * 32 + kl;
        const float v = W[(size_t)k * D_ + nt * 16 + c16];
        unsigned short h, l;
        split_bf16(v, h, l);
        const int lane = c16 + 16 * ((kl >> 3) & 3);
        const int e    = kl & 7;
        const size_t pb = (((size_t)nt * 8 + ks) * 4 + mat * 2) * 512 + lane * 8 + e;
        Wpk[pb]       = h;
        Wpk[pb + 512] = l;
    }
}

// ---------------- K2: TEXT gather from bf16 table -> xb_t bf16 ----------------
template<bool BF16TAB>
__global__ __launch_bounds__(256) void textg_kernel(
    const int*   __restrict__ text_ids,
    const int*   __restrict__ text_len,
    const float* __restrict__ word_emb,
    const unsigned short* __restrict__ wtab,
    unsigned short* __restrict__ xb_t)   // [NN, D] bf16
{
    __shared__ int   sIds[LT_];
    __shared__ float red[8][D_];

    const int n    = blockIdx.x;
    const int tid  = threadIdx.x;
    const int wave = tid >> 6;
    const int lane = tid & 63;

    if (tid < LT_) sIds[tid] = text_ids[(size_t)n * LT_ + tid];
    const int lt = text_len[n];
    __syncthreads();

    float t;
    if (BF16TAB) {
        float ta[8];
        #pragma unroll
        for (int j = 0; j < 8; ++j) ta[j] = 0.f;
        const int h  = lane >> 5;
        const int cg = lane & 31;
        const int s  = wave * 2 + h;               // sub-stream 0..7
        const unsigned short* __restrict__ bp = wtab + cg * 8;
        #pragma unroll 4
        for (int l = s; l < lt; l += 8) {
            const bf16x8 v = *reinterpret_cast<const bf16x8*>(bp + (size_t)sIds[l] * D_);
            #pragma unroll
            for (int j = 0; j < 8; ++j) ta[j] += bf2f((unsigned short)v[j]);
        }
        *reinterpret_cast<float4*>(&red[s][cg * 8])     = make_float4(ta[0], ta[1], ta[2], ta[3]);
        *reinterpret_cast<float4*>(&red[s][cg * 8 + 4]) = make_float4(ta[4], ta[5], ta[6], ta[7]);
        __syncthreads();
        t = ((red[0][tid] + red[1][tid]) + (red[2][tid] + red[3][tid]))
          + ((red[4][tid] + red[5][tid]) + (red[6][tid] + red[7][tid]));
    } else {
        float4 a4 = make_float4(0.f, 0.f, 0.f, 0.f);
        const float* __restrict__ bp = word_emb + (size_t)lane * 4;
        #pragma unroll 8
        for (int l = wave; l < lt; l += 4) {
            const float4 v = *reinterpret_cast<const float4*>(bp + (size_t)sIds[l] * D_);
            a4.x += v.x; a4.y += v.y; a4.z += v.z; a4.w += v.w;
        }
        *reinterpret_cast<float4*>(&red[wave][lane * 4]) = a4;
        __syncthreads();
        t = (red[0][tid] + red[1][tid]) + (red[2][tid] + red[3][tid]);
    }
    t /= (float)lt;
    xb_t[(size_t)n * D_ + tid] = f2bf_rne(t);
}

// ---------------- K3: MFMA projection -> h_comb bf16 ----------
// 1024 blocks x 256 thr: block = (node-tile(256), col-quarter(4)); wave owns
// col-tile nt = cq*4 + w. 4 MFMAs/ks. 2-stage pipeline. (proven R12/R13)
__global__ __launch_bounds__(256, 4) void proj_kernel(
    const unsigned short* __restrict__ xb_t,
    const unsigned short* __restrict__ xb_l,
    const unsigned short* __restrict__ Wpk,
    const float* __restrict__ w_adap,
    unsigned short* __restrict__ h_comb)   // [NN, D] bf16
{
    __shared__ __align__(16) short ldsX[2][16 * D_];   // 16 KB

    const int tid   = threadIdx.x;
    const int wave  = tid >> 6;
    const int lane  = tid & 63;
    const int ntile = blockIdx.x >> 2;
    const int cq    = blockIdx.x & 3;
    const int base  = ntile * 16;

    #pragma unroll
    for (int r = 0; r < 2; ++r) {
        const int idx = tid + 256 * r;     // 0..511
        const int nd  = idx >> 5, ch = idx & 31;
        const size_t g = (size_t)(base + nd) * D_ + ch * 8;
        const int d = nd * D_ + ((ch ^ (nd & 7)) * 8);
        *reinterpret_cast<int4*>(&ldsX[0][d]) = *reinterpret_cast<const int4*>(&xb_t[g]);
        *reinterpret_cast<int4*>(&ldsX[1][d]) = *reinterpret_cast<const int4*>(&xb_l[g]);
    }
    __syncthreads();

    const int nt  = cq * 4 + wave;
    const int row = lane & 15;
    const int kc  = lane >> 4;
    const unsigned short* __restrict__ WpB = Wpk + ((size_t)nt * 8) * 4 * 512 + lane * 8;

    f32x4 accT = {0.f, 0.f, 0.f, 0.f};
    f32x4 accL = {0.f, 0.f, 0.f, 0.f};

    bf16x8 cA0, cA1, cB0, cB1, cB2, cB3;
    bf16x8 nA0, nA1, nB0, nB1, nB2, nB3;

    {
        const int aidx = row * D_ + ((kc ^ (row & 7)) * 8);
        cA0 = *reinterpret_cast<const bf16x8*>(&ldsX[0][aidx]);
        cA1 = *reinterpret_cast<const bf16x8*>(&ldsX[1][aidx]);
        const unsigned short* p = WpB;
        cB0 = *reinterpret_cast<const bf16x8*>(p);
        cB1 = *reinterpret_cast<const bf16x8*>(p + 512);
        cB2 = *reinterpret_cast<const bf16x8*>(p + 1024);
        cB3 = *reinterpret_cast<const bf16x8*>(p + 1536);
    }

    #pragma unroll
    for (int ks = 0; ks < 8; ++ks) {
        if (ks < 7) {
            const int aidx = row * D_ + ((((ks + 1) * 4 + kc) ^ (row & 7)) * 8);
            nA0 = *reinterpret_cast<const bf16x8*>(&ldsX[0][aidx]);
            nA1 = *reinterpret_cast<const bf16x8*>(&ldsX[1][aidx]);
            const unsigned short* p = WpB + (size_t)(ks + 1) * 2048;
            nB0 = *reinterpret_cast<const bf16x8*>(p);
            nB1 = *reinterpret_cast<const bf16x8*>(p + 512);
            nB2 = *reinterpret_cast<const bf16x8*>(p + 1024);
            nB3 = *reinterpret_cast<const bf16x8*>(p + 1536);
        }

        accT = __builtin_amdgcn_mfma_f32_16x16x32_bf16(cA0, cB0, accT, 0, 0, 0);
        accT = __builtin_amdgcn_mfma_f32_16x16x32_bf16(cA0, cB1, accT, 0, 0, 0);
        accL = __builtin_amdgcn_mfma_f32_16x16x32_bf16(cA1, cB2, accL, 0, 0, 0);
        accL = __builtin_amdgcn_mfma_f32_16x16x32_bf16(cA1, cB3, accL, 0, 0, 0);

        cA0 = nA0; cA1 = nA1;
        cB0 = nB0; cB1 = nB1; cB2 = nB2; cB3 = nB3;
    }

    const float w0r = w_adap[0] * (1.0f / (float)NPG_);
    const float w1r = w_adap[1] * (1.0f / (float)NPG_);
    #pragma unroll
    for (int r = 0; r < 4; ++r) {
        const int node = base + kc * 4 + r;
        const int col  = nt * 16 + row;
        const float ht = accT[r] > 0.f ? accT[r] : 0.f;
        const float hl = accL[r] > 0.f ? accL[r] : 0.f;
        h_comb[(size_t)node * D_ + col] = f2bf_rne(w0r * ht + w1r * hl);
    }
}

// ---------------- K4: per-graph readout + MLP (h_comb bf16) ----------------
__global__ __launch_bounds__(256) void graph_kernel(
    const unsigned short* __restrict__ h_comb,   // [NN, D] bf16
    const float* __restrict__ W1,
    const float* __restrict__ b1,
    const float* __restrict__ Wout,
    const float* __restrict__ bout,
    float*       __restrict__ out)
{
    __shared__ float fused[D_];
    __shared__ float hrow[D_];

    const int bx   = blockIdx.x;
    const int b    = bx >> 2;
    const int part = bx & 3;
    const int tid  = threadIdx.x;

    float acc = 0.f;
    const unsigned short* __restrict__ basep = h_comb + (size_t)b * NPG_ * D_ + tid;
    #pragma unroll 8
    for (int n = 0; n < NPG_; ++n) acc += bf2f(basep[(size_t)n * D_]);
    fused[tid] = acc;
    __syncthreads();

    {
        float s0 = 0.f, s1 = 0.f, s2 = 0.f, s3 = 0.f;
        const float* __restrict__ wp = W1 + tid;
        for (int d = 0; d < D_; d += 4) {
            s0 = fmaf(fused[d + 0], wp[(size_t)(d + 0) * D_], s0);
            s1 = fmaf(fused[d + 1], wp[(size_t)(d + 1) * D_], s1);
            s2 = fmaf(fused[d + 2], wp[(size_t)(d + 2) * D_], s2);
            s3 = fmaf(fused[d + 3], wp[(size_t)(d + 3) * D_], s3);
        }
        const float a1 = b1[tid] + ((s0 + s1) + (s2 + s3));
        hrow[tid] = a1 > 0.f ? a1 : 0.f;
    }
    __syncthreads();

    const int j = part * 256 + tid;
    {
        float s0 = 0.f, s1 = 0.f, s2 = 0.f, s3 = 0.f;
        const float* __restrict__ wp = Wout + j;
        for (int d = 0; d < D_; d += 4) {
            s0 = fmaf(hrow[d + 0], wp[(size_t)(d + 0) * OUT_], s0);
            s1 = fmaf(hrow[d + 1], wp[(size_t)(d + 1) * OUT_], s1);
            s2 = fmaf(hrow[d + 2], wp[(size_t)(d + 2) * OUT_], s2);
            s3 = fmaf(hrow[d + 3], wp[(size_t)(d + 3) * OUT_], s3);
        }
        out[(size_t)b * OUT_ + j] = bout[j] + ((s0 + s1) + (s2 + s3));
    }
}

extern "C" void kernel_launch(void* const* d_in, const int* in_sizes, int n_in,
                              void* d_out, int out_size, void* d_ws, size_t ws_size,
                              hipStream_t stream) {
    const int*   text_ids  = (const int*)  d_in[0];
    const int*   label_ids = (const int*)  d_in[1];
    const int*   text_len  = (const int*)  d_in[2];
    const int*   label_len = (const int*)  d_in[3];
    const float* word_emb  = (const float*)d_in[4];
    const float* label_emb = (const float*)d_in[5];
    const float* Wg_text   = (const float*)d_in[6];
    const float* Wg_label  = (const float*)d_in[7];
    const float* w_adap    = (const float*)d_in[8];
    const float* W1        = (const float*)d_in[9];
    const float* b1        = (const float*)d_in[10];
    const float* Wout      = (const float*)d_in[11];
    const float* bout      = (const float*)d_in[12];

    // ws layout (byte offsets):
    //   [0, 2 MB)        h_comb  bf16 [NN][D]
    //   [4 MB, 6 MB)     xb_t bf16 [NN][D]
    //   [6 MB, 8 MB)     xb_l bf16 [NN][D]
    //   [8 MB, +512 KB)  Wpk packed bf16 B-fragments
    //   [9 MB, +25.6 MB) wtab bf16 word table (only if ws_size allows)
    char* ws = (char*)d_ws;
    unsigned short* h_comb = (unsigned short*)ws;
    unsigned short* xb_t   = (unsigned short*)(ws + (4 << 20));
    unsigned short* xb_l   = (unsigned short*)(ws + (6 << 20));
    unsigned short* Wpk    = (unsigned short*)(ws + (8 << 20));
    unsigned short* wtab   = (unsigned short*)(ws + (9 << 20));
    float*          out    = (float*)d_out;

    const size_t need = (size_t)(9 << 20) + (size_t)VOCAB_ * D_ * 2;
    const bool useBf16 = ws_size >= need;
    const int convBlocks = useBf16 ? 2048 : 0;

    prep_label_kernel<<<NN + convBlocks + 256, 256, 0, stream>>>(
        word_emb, Wg_text, Wg_label, convBlocks,
        label_ids, label_len, label_emb,
        wtab, Wpk, xb_l);

    if (useBf16) {
        textg_kernel<true><<<NN, 256, 0, stream>>>(
            text_ids, text_len, word_emb, wtab, xb_t);
    } else {
        textg_kernel<false><<<NN, 256, 0, stream>>>(
            text_ids, text_len, word_emb, wtab, xb_t);
    }

    proj_kernel<<<NN / 16 * 4, 256, 0, stream>>>(
        xb_t, xb_l, Wpk, w_adap, h_comb);

    graph_kernel<<<BG * 4, 256, 0, stream>>>(
        h_comb, W1, b1, Wout, bout, out);
}